// Round 3
// baseline (578.917 us; speedup 1.0000x reference)
//
#include <hip/hip_runtime.h>

// Problem constants: B=8, H=W=128, C=192, NH=6, hd=32, window 8x8 (64 tokens),
// 2048 windows total. Inputs/outputs are FP32 (reference dtype); internal
// compute uses bf16 MFMA with fp32 accumulation (harness threshold ~2% rel).

typedef __attribute__((ext_vector_type(8))) short bf16x8;
typedef __attribute__((ext_vector_type(4))) float f32x4;

__device__ __forceinline__ float bf2f(unsigned short h) {
    return __builtin_bit_cast(float, (unsigned int)h << 16);
}
__device__ __forceinline__ unsigned short f2bf(float f) {
    unsigned int u = __builtin_bit_cast(unsigned int, f);
    u += 0x7fffu + ((u >> 16) & 1u);   // round-to-nearest-even
    return (unsigned short)(u >> 16);
}
__device__ __forceinline__ bf16x8 ld8(const unsigned short* p) {   // LDS bf16 x8
    return *(const bf16x8*)p;
}
__device__ __forceinline__ bf16x8 ldf8(const float* p) {           // global fp32 x8 -> bf16x8
    float4 a = *(const float4*)p;
    float4 b = *(const float4*)(p + 4);
    bf16x8 r;
    r[0] = (short)f2bf(a.x); r[1] = (short)f2bf(a.y);
    r[2] = (short)f2bf(a.z); r[3] = (short)f2bf(a.w);
    r[4] = (short)f2bf(b.x); r[5] = (short)f2bf(b.y);
    r[6] = (short)f2bf(b.z); r[7] = (short)f2bf(b.w);
    return r;
}

// ---------------------------------------------------------------------------
// K0: repack w_qkv (192x576) and w_proj (192x192), fp32 -> bf16, into MFMA
// B-fragment order:
//   wm[((kt*NT + nt)*64 + lane)*8 + j] = W[(kt*32 + (lane>>4)*8 + j)*N + nt*16 + (lane&15)]
// so a GEMM B-frag load is one coalesced 16B read per lane.
// ---------------------------------------------------------------------------
__global__ __launch_bounds__(256) void repack_kernel(
    const float* __restrict__ w_qkv,
    const float* __restrict__ w_proj,
    unsigned short* __restrict__ wq_m,
    unsigned short* __restrict__ wp_m)
{
    int f = blockIdx.x * 256 + threadIdx.x;
    if (f < 6 * 36 * 64 * 8) {            // 110592
        int j = f & 7, lane = (f >> 3) & 63, rest = f >> 9;
        int nt = rest % 36, kt = rest / 36;
        wq_m[f] = f2bf(w_qkv[(kt * 32 + (lane >> 4) * 8 + j) * 576 + nt * 16 + (lane & 15)]);
    }
    if (f < 6 * 12 * 64 * 8) {            // 36864
        int j = f & 7, lane = (f >> 3) & 63, rest = f >> 9;
        int nt = rest % 12, kt = rest / 12;
        wp_m[f] = f2bf(w_proj[(kt * 32 + (lane >> 4) * 8 + j) * 192 + nt * 16 + (lane & 15)]);
    }
}

// ---------------------------------------------------------------------------
// K1: per-window fused QKV projection + attention.
// Block = 256 threads (4 waves), one block per 8x8 window.
// MFMA fragment conventions (16x16x32 bf16):
//   a[j] = A[lane&15][quad*8+j]; b[j] = B[quad*8+j][lane&15];
//   d[r] = D[quad*4+r][lane&15]   (quad = lane>>4)
// ---------------------------------------------------------------------------
__global__ __launch_bounds__(256, 2) void qkv_attn_kernel(
    const float* __restrict__ x,
    const unsigned short* __restrict__ wq_m,
    const float* __restrict__ b_qkv,
    unsigned short* __restrict__ o_scr)
{
    __shared__ unsigned short qs[64 * 104];   // 3 heads x 32 dims (pad 96->104), q pre-scaled
    __shared__ unsigned short ks[64 * 104];
    __shared__ unsigned short vT[96 * 72];    // vT[dim_local][token], pad 64->72
    __shared__ unsigned short Ps[64 * 72];    // P (unnormalized softmax), pad 64->72

    const int tid  = threadIdx.x;
    const int lane = tid & 63;
    const int wave = tid >> 6;
    const int l16  = lane & 15;
    const int quad = lane >> 4;

    const int img  = blockIdx.x >> 8;
    const int wrem = blockIdx.x & 255;
    const int y0 = (wrem >> 4) * 8;
    const int x0 = (wrem & 15) * 8;

    // A-operand row pointers (token rows of this window), per M-tile
    const float* xrow[4];
#pragma unroll
    for (int mt = 0; mt < 4; ++mt) {
        int token = mt * 16 + l16;
        int tr = token >> 3, tc = token & 7;
        xrow[mt] = x + ((img * 128 + y0 + tr) * 128 + (x0 + tc)) * 192;
    }

    // N-tile assignment: 18 tiles (6 q, 6 k, 6 v) over 4 waves: 5,5,4,4
    const int cnt   = (wave < 2) ? 5 : 4;
    const int start = (wave < 2) ? wave * 5 : 10 + (wave - 2) * 4;

    for (int p = 0; p < 2; ++p) {          // head-group pass: heads 3p..3p+2
        int nt_g[5], sec[5], tl[5];
#pragma unroll
        for (int s = 0; s < 5; ++s) {
            int ti = start + s;
            int sc = ti / 6;               // 0=q,1=k,2=v (garbage for unused s, guarded)
            int t  = ti - sc * 6;
            sec[s] = sc; tl[s] = t; nt_g[s] = sc * 12 + p * 6 + t;  // tile idx in [0,36)
        }

        f32x4 acc[5][4];
#pragma unroll
        for (int s = 0; s < 5; ++s)
#pragma unroll
            for (int mt = 0; mt < 4; ++mt)
                acc[s][mt] = (f32x4){0.f, 0.f, 0.f, 0.f};

        for (int kt = 0; kt < 6; ++kt) {
            bf16x8 af[4];
#pragma unroll
            for (int mt = 0; mt < 4; ++mt)
                af[mt] = ldf8(xrow[mt] + kt * 32 + quad * 8);
#pragma unroll
            for (int s = 0; s < 5; ++s) {
                if (s < cnt) {
                    bf16x8 bw = ld8(wq_m + (((kt * 36 + nt_g[s]) * 64 + lane) << 3));
#pragma unroll
                    for (int mt = 0; mt < 4; ++mt)
                        acc[s][mt] = __builtin_amdgcn_mfma_f32_16x16x32_bf16(
                            af[mt], bw, acc[s][mt], 0, 0, 0);
                }
            }
        }

        // epilogue: +bias, (q scaled by hd^-0.5), scatter to LDS
#pragma unroll
        for (int s = 0; s < 5; ++s) {
            if (s < cnt) {
                int colg = nt_g[s] * 16 + l16;           // column in [0,576)
                float bias = b_qkv[colg];
#pragma unroll
                for (int mt = 0; mt < 4; ++mt) {
#pragma unroll
                    for (int r = 0; r < 4; ++r) {
                        int token = mt * 16 + quad * 4 + r;
                        float v = acc[s][mt][r] + bias;
                        if (sec[s] == 0)
                            qs[token * 104 + tl[s] * 16 + l16] = f2bf(v * 0.17677669529663687f);
                        else if (sec[s] == 1)
                            ks[token * 104 + tl[s] * 16 + l16] = f2bf(v);
                        else
                            vT[(tl[s] * 16 + l16) * 72 + token] = f2bf(v);
                    }
                }
            }
        }
        __syncthreads();

        // attention: each wave owns token stripe [wave*16, wave*16+16)
        for (int i = 0; i < 3; ++i) {
            bf16x8 aq = ld8(qs + (wave * 16 + l16) * 104 + i * 32 + quad * 8);
            f32x4 sc4[4];
#pragma unroll
            for (int nt = 0; nt < 4; ++nt) {
                sc4[nt] = (f32x4){0.f, 0.f, 0.f, 0.f};
                bf16x8 bk = ld8(ks + (nt * 16 + l16) * 104 + i * 32 + quad * 8);
                sc4[nt] = __builtin_amdgcn_mfma_f32_16x16x32_bf16(aq, bk, sc4[nt], 0, 0, 0);
            }
            // softmax over 64 cols: 4 in-register tiles + 16-lane quad shuffles
            float linv[4];
#pragma unroll
            for (int r = 0; r < 4; ++r) {
                float m = fmaxf(fmaxf(sc4[0][r], sc4[1][r]), fmaxf(sc4[2][r], sc4[3][r]));
                m = fmaxf(m, __shfl_xor(m, 1, 64));
                m = fmaxf(m, __shfl_xor(m, 2, 64));
                m = fmaxf(m, __shfl_xor(m, 4, 64));
                m = fmaxf(m, __shfl_xor(m, 8, 64));
                float pv[4], sum = 0.f;
#pragma unroll
                for (int nt = 0; nt < 4; ++nt) {
                    pv[nt] = __expf(sc4[nt][r] - m);
                    sum += pv[nt];
                }
                sum += __shfl_xor(sum, 1, 64);
                sum += __shfl_xor(sum, 2, 64);
                sum += __shfl_xor(sum, 4, 64);
                sum += __shfl_xor(sum, 8, 64);
                linv[r] = 1.f / sum;
                int row = wave * 16 + quad * 4 + r;
#pragma unroll
                for (int nt = 0; nt < 4; ++nt)
                    Ps[row * 72 + nt * 16 + l16] = f2bf(pv[nt]);
            }
            __syncthreads();   // fence Ps writes -> PV reads
            // PV: o(16x32) = P(16x64) * V(64x32)
            f32x4 o4[2];
            o4[0] = (f32x4){0.f, 0.f, 0.f, 0.f};
            o4[1] = (f32x4){0.f, 0.f, 0.f, 0.f};
#pragma unroll
            for (int kt2 = 0; kt2 < 2; ++kt2) {
                bf16x8 ap = ld8(Ps + (wave * 16 + l16) * 72 + kt2 * 32 + quad * 8);
#pragma unroll
                for (int nt = 0; nt < 2; ++nt) {
                    bf16x8 bv = ld8(vT + (i * 32 + nt * 16 + l16) * 72 + kt2 * 32 + quad * 8);
                    o4[nt] = __builtin_amdgcn_mfma_f32_16x16x32_bf16(ap, bv, o4[nt], 0, 0, 0);
                }
            }
            int h = p * 3 + i;
#pragma unroll
            for (int nt = 0; nt < 2; ++nt) {
#pragma unroll
                for (int r = 0; r < 4; ++r) {
                    int token = wave * 16 + quad * 4 + r;
                    int tr = token >> 3, tc = token & 7;
                    o_scr[((img * 128 + y0 + tr) * 128 + (x0 + tc)) * 192
                          + h * 32 + nt * 16 + l16] = f2bf(o4[nt][r] * linv[r]);
                }
            }
            __syncthreads();   // fence PV reads -> next iteration's Ps writes
        }
        __syncthreads();   // LDS buffers reused by next pass
    }
}

// ---------------------------------------------------------------------------
// K2: fused depthwise 3x3 conv (pad 1) + output projection.
// Block = 256 threads, one block per 8x8 pixel tile. Halo 10x10x192 (bf16) in
// LDS, fp32 conv -> cb LDS (bf16), then 64x192 @ 192x192 MFMA proj, fp32 out.
// ---------------------------------------------------------------------------
__global__ __launch_bounds__(256, 2) void conv_proj_kernel(
    const unsigned short* __restrict__ o_scr,
    const float* __restrict__ w_dw,
    const float* __restrict__ b_dw,
    const unsigned short* __restrict__ wp_m,
    const float* __restrict__ b_proj,
    float* __restrict__ out)
{
    __shared__ unsigned short oh[100 * 192];  // 10x10 halo, token-major, 38400 B
    __shared__ unsigned short cb[64 * 200];   // conv result, pad 192->200, 25600 B

    const int tid  = threadIdx.x;
    const int lane = tid & 63;
    const int wave = tid >> 6;
    const int l16  = lane & 15;
    const int quad = lane >> 4;

    const int img  = blockIdx.x >> 8;
    const int wrem = blockIdx.x & 255;
    const int y0 = (wrem >> 4) * 8;
    const int x0 = (wrem & 15) * 8;

    // halo load: 100 pixels x 24 uint4 chunks (8 bf16 each), zero-pad OOB
    for (int c = tid; c < 2400; c += 256) {
        int pix = c / 24, ck = c % 24;
        int py = y0 - 1 + pix / 10;
        int px = x0 - 1 + pix % 10;
        uint4 v = {0u, 0u, 0u, 0u};
        if (py >= 0 && py < 128 && px >= 0 && px < 128)
            v = *(const uint4*)(o_scr + ((img * 128 + py) * 128 + px) * 192 + ck * 8);
        *(uint4*)(oh + pix * 192 + ck * 8) = v;
    }
    __syncthreads();

    // depthwise conv, fp32 accum (weights read fp32 from global, L1-cached)
    for (int idx = tid; idx < 64 * 192; idx += 256) {
        int ch = idx % 192;
        int t  = idx / 192;
        int r = t >> 3, cc = t & 7;
        float a = b_dw[ch];
#pragma unroll
        for (int dy = 0; dy < 3; ++dy)
#pragma unroll
            for (int dx = 0; dx < 3; ++dx)
                a += bf2f(oh[((r + dy) * 10 + (cc + dx)) * 192 + ch])
                   * w_dw[(dy * 3 + dx) * 192 + ch];
        cb[t * 200 + ch] = f2bf(a);
    }
    __syncthreads();

    // proj GEMM: M=64 (4 mt), N=192 (12 nt: 3 per wave), K=192 (6 kt)
    f32x4 po[3][4];
#pragma unroll
    for (int n = 0; n < 3; ++n)
#pragma unroll
        for (int mt = 0; mt < 4; ++mt)
            po[n][mt] = (f32x4){0.f, 0.f, 0.f, 0.f};

    for (int kt = 0; kt < 6; ++kt) {
        bf16x8 af[4];
#pragma unroll
        for (int mt = 0; mt < 4; ++mt)
            af[mt] = ld8(cb + (mt * 16 + l16) * 200 + kt * 32 + quad * 8);
#pragma unroll
        for (int ntl = 0; ntl < 3; ++ntl) {
            int nt = wave * 3 + ntl;
            bf16x8 bw = ld8(wp_m + (((kt * 12 + nt) * 64 + lane) << 3));
#pragma unroll
            for (int mt = 0; mt < 4; ++mt)
                po[ntl][mt] = __builtin_amdgcn_mfma_f32_16x16x32_bf16(
                    af[mt], bw, po[ntl][mt], 0, 0, 0);
        }
    }

#pragma unroll
    for (int ntl = 0; ntl < 3; ++ntl) {
        int col = (wave * 3 + ntl) * 16 + l16;
        float bias = b_proj[col];
#pragma unroll
        for (int mt = 0; mt < 4; ++mt) {
#pragma unroll
            for (int r = 0; r < 4; ++r) {
                int t = mt * 16 + quad * 4 + r;
                out[((img * 128 + y0 + (t >> 3)) * 128 + (x0 + (t & 7))) * 192 + col]
                    = po[ntl][mt][r] + bias;
            }
        }
    }
}

// ---------------------------------------------------------------------------
extern "C" void kernel_launch(void* const* d_in, const int* in_sizes, int n_in,
                              void* d_out, int out_size, void* d_ws, size_t ws_size,
                              hipStream_t stream)
{
    const float* x      = (const float*)d_in[0];
    const float* w_qkv  = (const float*)d_in[1];
    const float* b_qkv  = (const float*)d_in[2];
    const float* w_dw   = (const float*)d_in[3];
    const float* b_dw   = (const float*)d_in[4];
    const float* w_proj = (const float*)d_in[5];
    const float* b_proj = (const float*)d_in[6];
    float* out = (float*)d_out;

    // ws layout: [wq_m 110592 u16][wp_m 36864 u16][o_scr 25165824 u16] ~= 48.3 MiB
    unsigned short* wq_m  = (unsigned short*)d_ws;
    unsigned short* wp_m  = wq_m + 110592;
    unsigned short* o_scr = wq_m + 147456;

    repack_kernel<<<dim3(432), dim3(256), 0, stream>>>(w_qkv, w_proj, wq_m, wp_m);
    qkv_attn_kernel<<<dim3(2048), dim3(256), 0, stream>>>(x, wq_m, b_qkv, o_scr);
    conv_proj_kernel<<<dim3(2048), dim3(256), 0, stream>>>(o_scr, w_dw, b_dw, wp_m, b_proj, out);
}

// Round 4
// 351.587 us; speedup vs baseline: 1.6466x; 1.6466x over previous
//
#include <hip/hip_runtime.h>

// Problem: B=8, H=W=128, C=192, NH=6, hd=32, window 8x8 (64 tok), 2048 windows.
// FP32 I/O; bf16 MFMA internally (threshold ~2% rel).

typedef __attribute__((ext_vector_type(8))) short bf16x8;
typedef __attribute__((ext_vector_type(4))) float f32x4;

__device__ __forceinline__ float bf2f(unsigned short h) {
    return __builtin_bit_cast(float, (unsigned int)h << 16);
}
__device__ __forceinline__ unsigned short f2bf(float f) {
    unsigned int u = __builtin_bit_cast(unsigned int, f);
    u += 0x7fffu + ((u >> 16) & 1u);
    return (unsigned short)(u >> 16);
}
__device__ __forceinline__ bf16x8 ld8(const unsigned short* p) {
    return *(const bf16x8*)p;
}
__device__ __forceinline__ bf16x8 ldf8(const float* p) {
    float4 a = *(const float4*)p;
    float4 b = *(const float4*)(p + 4);
    bf16x8 r;
    r[0] = (short)f2bf(a.x); r[1] = (short)f2bf(a.y);
    r[2] = (short)f2bf(a.z); r[3] = (short)f2bf(a.w);
    r[4] = (short)f2bf(b.x); r[5] = (short)f2bf(b.y);
    r[6] = (short)f2bf(b.z); r[7] = (short)f2bf(b.w);
    return r;
}

// ---------------------------------------------------------------------------
// K0: repack w_qkv/w_proj (fp32) into bf16 MFMA B-fragment order.
// ---------------------------------------------------------------------------
__global__ __launch_bounds__(256) void repack_kernel(
    const float* __restrict__ w_qkv, const float* __restrict__ w_proj,
    unsigned short* __restrict__ wq_m, unsigned short* __restrict__ wp_m)
{
    int f = blockIdx.x * 256 + threadIdx.x;
    if (f < 6 * 36 * 64 * 8) {
        int j = f & 7, lane = (f >> 3) & 63, rest = f >> 9;
        int nt = rest % 36, kt = rest / 36;
        wq_m[f] = f2bf(w_qkv[(kt * 32 + (lane >> 4) * 8 + j) * 576 + nt * 16 + (lane & 15)]);
    }
    if (f < 6 * 12 * 64 * 8) {
        int j = f & 7, lane = (f >> 3) & 63, rest = f >> 9;
        int nt = rest % 12, kt = rest / 12;
        wp_m[f] = f2bf(w_proj[(kt * 32 + (lane >> 4) * 8 + j) * 192 + nt * 16 + (lane & 15)]);
    }
}

// ---------------------------------------------------------------------------
// K_A: QKV GEMM per window. 4 waves x 9 N-tiles, 36 independent MFMA chains,
// no barrier in main loop. q/k stored [wi][h][tok][dim] (32B-run scatter);
// v transposed via LDS -> v_scr[wi][dim(0..191)][tok] with coalesced stores.
// Frags: a[j]=A[l16][quad*8+j]; b[j]=B[quad*8+j][l16]; d[r]=D[quad*4+r][l16].
// ---------------------------------------------------------------------------
__global__ __launch_bounds__(256, 2) void qkv_gemm_kernel(
    const float* __restrict__ x, const unsigned short* __restrict__ wq_m,
    const float* __restrict__ b_qkv,
    unsigned short* __restrict__ q_scr, unsigned short* __restrict__ k_scr,
    unsigned short* __restrict__ v_scr)
{
    __shared__ unsigned short vbuf[192 * 72];   // [dim][tok], stride 72 (2-way free)

    const int tid = threadIdx.x, lane = tid & 63, wave = tid >> 6;
    const int l16 = lane & 15, quad = lane >> 4;
    const int wi = blockIdx.x;
    const int img = wi >> 8, wrem = wi & 255;
    const int y0 = (wrem >> 4) * 8, x0 = (wrem & 15) * 8;

    const float* xrow[4];
#pragma unroll
    for (int mt = 0; mt < 4; ++mt) {
        int token = mt * 16 + l16;
        xrow[mt] = x + ((img * 128 + y0 + (token >> 3)) * 128 + (x0 + (token & 7))) * 192;
    }

    f32x4 acc[9][4];
#pragma unroll
    for (int s = 0; s < 9; ++s)
#pragma unroll
        for (int mt = 0; mt < 4; ++mt) acc[s][mt] = (f32x4){0.f, 0.f, 0.f, 0.f};

    for (int kt = 0; kt < 6; ++kt) {
        bf16x8 af[4];
#pragma unroll
        for (int mt = 0; mt < 4; ++mt) af[mt] = ldf8(xrow[mt] + kt * 32 + quad * 8);
#pragma unroll
        for (int s = 0; s < 9; ++s) {
            bf16x8 bw = ld8(wq_m + (((kt * 36 + wave * 9 + s) * 64 + lane) << 3));
#pragma unroll
            for (int mt = 0; mt < 4; ++mt)
                acc[s][mt] = __builtin_amdgcn_mfma_f32_16x16x32_bf16(af[mt], bw, acc[s][mt], 0, 0, 0);
        }
    }

#pragma unroll
    for (int s = 0; s < 9; ++s) {
        int nt = wave * 9 + s;
        int sec = nt / 12, loc = nt % 12, head = loc >> 1, dh = loc & 1;
        float bias = b_qkv[nt * 16 + l16];
        if (sec == 2) {          // v -> LDS transpose buffer [dim][tok]
            int dim = loc * 16 + l16;
#pragma unroll
            for (int mt = 0; mt < 4; ++mt)
#pragma unroll
                for (int r = 0; r < 4; ++r)
                    vbuf[dim * 72 + mt * 16 + quad * 4 + r] = f2bf(acc[s][mt][r] + bias);
        } else {
            unsigned short* dst = (sec == 0 ? q_scr : k_scr)
                                + ((wi * 6 + head) * 64) * 32 + dh * 16 + l16;
            float scl = (sec == 0) ? 0.17677669529663687f : 1.0f;
#pragma unroll
            for (int mt = 0; mt < 4; ++mt)
#pragma unroll
                for (int r = 0; r < 4; ++r)
                    dst[(mt * 16 + quad * 4 + r) * 32] = f2bf((acc[s][mt][r] + bias) * scl);
        }
    }
    __syncthreads();

    // coalesced v readout: 1536 x 16B stores
#pragma unroll
    for (int k = 0; k < 6; ++k) {
        int idx = k * 256 + tid;
        int oct = idx & 7, dim = idx >> 3;      // dim in [0,192)
        bf16x8 t8 = ld8(&vbuf[dim * 72 + oct * 8]);
        *(bf16x8*)&v_scr[(wi * 192 + dim) * 64 + oct * 8] = t8;
    }
}

// ---------------------------------------------------------------------------
// K_B: attention, 1 wave per (window, head). Block=64, one barrier total.
// ---------------------------------------------------------------------------
__global__ __launch_bounds__(64) void attn_kernel(
    const unsigned short* __restrict__ q_scr, const unsigned short* __restrict__ k_scr,
    const unsigned short* __restrict__ v_scr, unsigned short* __restrict__ o_scr)
{
    __shared__ unsigned short Ps[64 * 72];   // normalized P, stride 72 (16B-aligned rows)

    const int lane = threadIdx.x, l16 = lane & 15, quad = lane >> 4;
    const int h = blockIdx.x, wi = blockIdx.y;
    const int img = wi >> 8, wrem = wi & 255;
    const int y0 = (wrem >> 4) * 8, x0 = (wrem & 15) * 8;

    const unsigned short* qb = q_scr + ((wi * 6 + h) * 64) * 32;
    const unsigned short* kb = k_scr + ((wi * 6 + h) * 64) * 32;

    bf16x8 aq[4], bk[4];
#pragma unroll
    for (int mt = 0; mt < 4; ++mt) aq[mt] = ld8(qb + (mt * 16 + l16) * 32 + quad * 8);
#pragma unroll
    for (int nt = 0; nt < 4; ++nt) bk[nt] = ld8(kb + (nt * 16 + l16) * 32 + quad * 8);

    f32x4 s[4][4];
#pragma unroll
    for (int mt = 0; mt < 4; ++mt)
#pragma unroll
        for (int nt = 0; nt < 4; ++nt) {
            s[mt][nt] = (f32x4){0.f, 0.f, 0.f, 0.f};
            s[mt][nt] = __builtin_amdgcn_mfma_f32_16x16x32_bf16(aq[mt], bk[nt], s[mt][nt], 0, 0, 0);
        }

    // softmax per row (row = mt*16+quad*4+r), cols split over 4 nt regs x 16 lanes
#pragma unroll
    for (int mt = 0; mt < 4; ++mt) {
#pragma unroll
        for (int r = 0; r < 4; ++r) {
            float m = fmaxf(fmaxf(s[mt][0][r], s[mt][1][r]), fmaxf(s[mt][2][r], s[mt][3][r]));
            m = fmaxf(m, __shfl_xor(m, 1, 64));
            m = fmaxf(m, __shfl_xor(m, 2, 64));
            m = fmaxf(m, __shfl_xor(m, 4, 64));
            m = fmaxf(m, __shfl_xor(m, 8, 64));
            float pv[4], sum = 0.f;
#pragma unroll
            for (int nt = 0; nt < 4; ++nt) { pv[nt] = __expf(s[mt][nt][r] - m); sum += pv[nt]; }
            sum += __shfl_xor(sum, 1, 64);
            sum += __shfl_xor(sum, 2, 64);
            sum += __shfl_xor(sum, 4, 64);
            sum += __shfl_xor(sum, 8, 64);
            float inv = 1.f / sum;
            int row = mt * 16 + quad * 4 + r;
#pragma unroll
            for (int nt = 0; nt < 4; ++nt)
                Ps[row * 72 + nt * 16 + l16] = f2bf(pv[nt] * inv);
        }
    }
    __syncthreads();

    f32x4 o[4][2];
#pragma unroll
    for (int mt = 0; mt < 4; ++mt)
#pragma unroll
        for (int n2 = 0; n2 < 2; ++n2) o[mt][n2] = (f32x4){0.f, 0.f, 0.f, 0.f};

#pragma unroll
    for (int kt2 = 0; kt2 < 2; ++kt2) {
        bf16x8 bv[2];
#pragma unroll
        for (int n2 = 0; n2 < 2; ++n2)
            bv[n2] = ld8(&v_scr[(wi * 192 + h * 32 + n2 * 16 + l16) * 64 + kt2 * 32 + quad * 8]);
#pragma unroll
        for (int mt = 0; mt < 4; ++mt) {
            bf16x8 ap = ld8(&Ps[(mt * 16 + l16) * 72 + kt2 * 32 + quad * 8]);
#pragma unroll
            for (int n2 = 0; n2 < 2; ++n2)
                o[mt][n2] = __builtin_amdgcn_mfma_f32_16x16x32_bf16(ap, bv[n2], o[mt][n2], 0, 0, 0);
        }
    }

#pragma unroll
    for (int mt = 0; mt < 4; ++mt)
#pragma unroll
        for (int n2 = 0; n2 < 2; ++n2)
#pragma unroll
            for (int r = 0; r < 4; ++r) {
                int token = mt * 16 + quad * 4 + r;
                o_scr[((img * 128 + y0 + (token >> 3)) * 128 + (x0 + (token & 7))) * 192
                      + h * 32 + n2 * 16 + l16] = f2bf(o[mt][n2][r]);
            }
}

// ---------------------------------------------------------------------------
// K_C: depthwise 3x3 (vectorized 8-ch) + proj GEMM.
// ---------------------------------------------------------------------------
__global__ __launch_bounds__(256, 2) void conv_proj_kernel(
    const unsigned short* __restrict__ o_scr,
    const float* __restrict__ w_dw, const float* __restrict__ b_dw,
    const unsigned short* __restrict__ wp_m, const float* __restrict__ b_proj,
    float* __restrict__ out)
{
    __shared__ unsigned short oh[100 * 192];
    __shared__ unsigned short cb[64 * 200];
    __shared__ float wdw_s[9 * 192];
    __shared__ float bdw_s[192];

    const int tid = threadIdx.x, lane = tid & 63, wave = tid >> 6;
    const int l16 = lane & 15, quad = lane >> 4;
    const int img = blockIdx.x >> 8, wrem = blockIdx.x & 255;
    const int y0 = (wrem >> 4) * 8, x0 = (wrem & 15) * 8;

    for (int i = tid; i < 9 * 192; i += 256) wdw_s[i] = w_dw[i];
    if (tid < 192) bdw_s[tid] = b_dw[tid];

    for (int c = tid; c < 2400; c += 256) {
        int pix = c / 24, ck = c % 24;
        int py = y0 - 1 + pix / 10, px = x0 - 1 + pix % 10;
        uint4 v = {0u, 0u, 0u, 0u};
        if (py >= 0 && py < 128 && px >= 0 && px < 128)
            v = *(const uint4*)(o_scr + ((img * 128 + py) * 128 + px) * 192 + ck * 8);
        *(uint4*)(oh + pix * 192 + ck * 8) = v;
    }
    __syncthreads();

    // conv: item = (token, 8-channel chunk); 6 items/thread
#pragma unroll
    for (int k = 0; k < 6; ++k) {
        int idx = k * 256 + tid;
        int c8 = idx % 24, t = idx / 24;
        int r = t >> 3, cc = t & 7;
        float a[8];
#pragma unroll
        for (int i = 0; i < 8; ++i) a[i] = bdw_s[c8 * 8 + i];
#pragma unroll
        for (int dy = 0; dy < 3; ++dy)
#pragma unroll
            for (int dx = 0; dx < 3; ++dx) {
                bf16x8 hv = ld8(&oh[((r + dy) * 10 + (cc + dx)) * 192 + c8 * 8]);
                const float* wp = &wdw_s[(dy * 3 + dx) * 192 + c8 * 8];
#pragma unroll
                for (int i = 0; i < 8; ++i)
                    a[i] += bf2f((unsigned short)hv[i]) * wp[i];
            }
        bf16x8 rv;
#pragma unroll
        for (int i = 0; i < 8; ++i) rv[i] = (short)f2bf(a[i]);
        *(bf16x8*)&cb[t * 200 + c8 * 8] = rv;
    }
    __syncthreads();

    f32x4 po[3][4];
#pragma unroll
    for (int n = 0; n < 3; ++n)
#pragma unroll
        for (int mt = 0; mt < 4; ++mt) po[n][mt] = (f32x4){0.f, 0.f, 0.f, 0.f};

    for (int kt = 0; kt < 6; ++kt) {
        bf16x8 af[4];
#pragma unroll
        for (int mt = 0; mt < 4; ++mt) af[mt] = ld8(cb + (mt * 16 + l16) * 200 + kt * 32 + quad * 8);
#pragma unroll
        for (int ntl = 0; ntl < 3; ++ntl) {
            bf16x8 bw = ld8(wp_m + (((kt * 12 + wave * 3 + ntl) * 64 + lane) << 3));
#pragma unroll
            for (int mt = 0; mt < 4; ++mt)
                po[ntl][mt] = __builtin_amdgcn_mfma_f32_16x16x32_bf16(af[mt], bw, po[ntl][mt], 0, 0, 0);
        }
    }

#pragma unroll
    for (int ntl = 0; ntl < 3; ++ntl) {
        int col = (wave * 3 + ntl) * 16 + l16;
        float bias = b_proj[col];
#pragma unroll
        for (int mt = 0; mt < 4; ++mt)
#pragma unroll
            for (int r = 0; r < 4; ++r) {
                int t = mt * 16 + quad * 4 + r;
                out[((img * 128 + y0 + (t >> 3)) * 128 + (x0 + (t & 7))) * 192 + col]
                    = po[ntl][mt][r] + bias;
            }
    }
}

// ---------------------------------------------------------------------------
// Fallback fused kernel (round-3 correct version) for small ws_size.
// ---------------------------------------------------------------------------
__global__ __launch_bounds__(256, 2) void qkv_attn_kernel(
    const float* __restrict__ x, const unsigned short* __restrict__ wq_m,
    const float* __restrict__ b_qkv, unsigned short* __restrict__ o_scr)
{
    __shared__ unsigned short qs[64 * 104];
    __shared__ unsigned short ks[64 * 104];
    __shared__ unsigned short vT[96 * 72];
    __shared__ unsigned short Ps[64 * 72];

    const int tid = threadIdx.x, lane = tid & 63, wave = tid >> 6;
    const int l16 = lane & 15, quad = lane >> 4;
    const int img = blockIdx.x >> 8, wrem = blockIdx.x & 255;
    const int y0 = (wrem >> 4) * 8, x0 = (wrem & 15) * 8;

    const float* xrow[4];
#pragma unroll
    for (int mt = 0; mt < 4; ++mt) {
        int token = mt * 16 + l16;
        xrow[mt] = x + ((img * 128 + y0 + (token >> 3)) * 128 + (x0 + (token & 7))) * 192;
    }
    const int cnt = (wave < 2) ? 5 : 4;
    const int start = (wave < 2) ? wave * 5 : 10 + (wave - 2) * 4;

    for (int p = 0; p < 2; ++p) {
        int nt_g[5], sec[5], tl[5];
#pragma unroll
        for (int s = 0; s < 5; ++s) {
            int ti = start + s, sc = ti / 6, t = ti - sc * 6;
            sec[s] = sc; tl[s] = t; nt_g[s] = sc * 12 + p * 6 + t;
        }
        f32x4 acc[5][4];
#pragma unroll
        for (int s = 0; s < 5; ++s)
#pragma unroll
            for (int mt = 0; mt < 4; ++mt) acc[s][mt] = (f32x4){0.f, 0.f, 0.f, 0.f};

        for (int kt = 0; kt < 6; ++kt) {
            bf16x8 af[4];
#pragma unroll
            for (int mt = 0; mt < 4; ++mt) af[mt] = ldf8(xrow[mt] + kt * 32 + quad * 8);
#pragma unroll
            for (int s = 0; s < 5; ++s)
                if (s < cnt) {
                    bf16x8 bw = ld8(wq_m + (((kt * 36 + nt_g[s]) * 64 + lane) << 3));
#pragma unroll
                    for (int mt = 0; mt < 4; ++mt)
                        acc[s][mt] = __builtin_amdgcn_mfma_f32_16x16x32_bf16(af[mt], bw, acc[s][mt], 0, 0, 0);
                }
        }
#pragma unroll
        for (int s = 0; s < 5; ++s)
            if (s < cnt) {
                float bias = b_qkv[nt_g[s] * 16 + l16];
#pragma unroll
                for (int mt = 0; mt < 4; ++mt)
#pragma unroll
                    for (int r = 0; r < 4; ++r) {
                        int token = mt * 16 + quad * 4 + r;
                        float v = acc[s][mt][r] + bias;
                        if (sec[s] == 0)      qs[token * 104 + tl[s] * 16 + l16] = f2bf(v * 0.17677669529663687f);
                        else if (sec[s] == 1) ks[token * 104 + tl[s] * 16 + l16] = f2bf(v);
                        else                  vT[(tl[s] * 16 + l16) * 72 + token] = f2bf(v);
                    }
            }
        __syncthreads();

        for (int i = 0; i < 3; ++i) {
            bf16x8 aq = ld8(qs + (wave * 16 + l16) * 104 + i * 32 + quad * 8);
            f32x4 sc4[4];
#pragma unroll
            for (int nt = 0; nt < 4; ++nt) {
                sc4[nt] = (f32x4){0.f, 0.f, 0.f, 0.f};
                bf16x8 bk = ld8(ks + (nt * 16 + l16) * 104 + i * 32 + quad * 8);
                sc4[nt] = __builtin_amdgcn_mfma_f32_16x16x32_bf16(aq, bk, sc4[nt], 0, 0, 0);
            }
            float linv[4];
#pragma unroll
            for (int r = 0; r < 4; ++r) {
                float m = fmaxf(fmaxf(sc4[0][r], sc4[1][r]), fmaxf(sc4[2][r], sc4[3][r]));
                m = fmaxf(m, __shfl_xor(m, 1, 64));
                m = fmaxf(m, __shfl_xor(m, 2, 64));
                m = fmaxf(m, __shfl_xor(m, 4, 64));
                m = fmaxf(m, __shfl_xor(m, 8, 64));
                float pv[4], sum = 0.f;
#pragma unroll
                for (int nt = 0; nt < 4; ++nt) { pv[nt] = __expf(sc4[nt][r] - m); sum += pv[nt]; }
                sum += __shfl_xor(sum, 1, 64);
                sum += __shfl_xor(sum, 2, 64);
                sum += __shfl_xor(sum, 4, 64);
                sum += __shfl_xor(sum, 8, 64);
                linv[r] = 1.f / sum;
                int row = wave * 16 + quad * 4 + r;
#pragma unroll
                for (int nt = 0; nt < 4; ++nt) Ps[row * 72 + nt * 16 + l16] = f2bf(pv[nt]);
            }
            __syncthreads();
            f32x4 o4[2];
            o4[0] = (f32x4){0.f, 0.f, 0.f, 0.f};
            o4[1] = (f32x4){0.f, 0.f, 0.f, 0.f};
#pragma unroll
            for (int kt2 = 0; kt2 < 2; ++kt2) {
                bf16x8 ap = ld8(Ps + (wave * 16 + l16) * 72 + kt2 * 32 + quad * 8);
#pragma unroll
                for (int nt = 0; nt < 2; ++nt) {
                    bf16x8 bv = ld8(vT + (i * 32 + nt * 16 + l16) * 72 + kt2 * 32 + quad * 8);
                    o4[nt] = __builtin_amdgcn_mfma_f32_16x16x32_bf16(ap, bv, o4[nt], 0, 0, 0);
                }
            }
            int h = p * 3 + i;
#pragma unroll
            for (int nt = 0; nt < 2; ++nt)
#pragma unroll
                for (int r = 0; r < 4; ++r) {
                    int token = wave * 16 + quad * 4 + r;
                    o_scr[((img * 128 + y0 + (token >> 3)) * 128 + (x0 + (token & 7))) * 192
                          + h * 32 + nt * 16 + l16] = f2bf(o4[nt][r] * linv[r]);
                }
            __syncthreads();
        }
        __syncthreads();
    }
}

// ---------------------------------------------------------------------------
extern "C" void kernel_launch(void* const* d_in, const int* in_sizes, int n_in,
                              void* d_out, int out_size, void* d_ws, size_t ws_size,
                              hipStream_t stream)
{
    const float* x      = (const float*)d_in[0];
    const float* w_qkv  = (const float*)d_in[1];
    const float* b_qkv  = (const float*)d_in[2];
    const float* w_dw   = (const float*)d_in[3];
    const float* b_dw   = (const float*)d_in[4];
    const float* w_proj = (const float*)d_in[5];
    const float* b_proj = (const float*)d_in[6];
    float* out = (float*)d_out;

    // ws (u16 units): wq_m 110592 | wp_m 36864 | o_scr 25165824 |
    //                 q_scr 25165824 | k_scr 25165824 | v_scr 25165824
    unsigned short* wq_m  = (unsigned short*)d_ws;
    unsigned short* wp_m  = wq_m + 110592;
    unsigned short* o_scr = wq_m + 147456;
    unsigned short* q_scr = wq_m + 25313280;
    unsigned short* k_scr = wq_m + 50479104;
    unsigned short* v_scr = wq_m + 75644928;

    bool fast = ws_size >= (size_t)100810752 * 2;

    repack_kernel<<<dim3(432), dim3(256), 0, stream>>>(w_qkv, w_proj, wq_m, wp_m);
    if (fast) {
        qkv_gemm_kernel<<<dim3(2048), dim3(256), 0, stream>>>(x, wq_m, b_qkv, q_scr, k_scr, v_scr);
        attn_kernel<<<dim3(6, 2048), dim3(64), 0, stream>>>(q_scr, k_scr, v_scr, o_scr);
    } else {
        qkv_attn_kernel<<<dim3(2048), dim3(256), 0, stream>>>(x, wq_m, b_qkv, o_scr);
    }
    conv_proj_kernel<<<dim3(2048), dim3(256), 0, stream>>>(o_scr, w_dw, b_dw, wp_m, b_proj, out);
}